// Round 8
// baseline (13115.036 us; speedup 1.0000x reference)
//
#include <hip/hip_runtime.h>

typedef __bf16 bf16;
typedef __bf16 bf16x4 __attribute__((ext_vector_type(4)));
typedef __bf16 bf16x8 __attribute__((ext_vector_type(8)));
typedef float f32x4 __attribute__((ext_vector_type(4)));
typedef int   i32x4 __attribute__((ext_vector_type(4)));
typedef unsigned long long u64;
typedef unsigned int u32;

#define T_STEPS 1024
#define BATCH   64
#define DIN     256
#define HID     1024
#define NFB     16            // feature-group blocks (64 features each)
#define SENT    0x7F7F7F7Fu   // two bf16 3.39e38 — unreachable by the RNN

// ---------------------------------------------------------------------------
// Kernel 1: xproj[t][b][h] = sum_d x[b][t][d] * w_ih[h][d]   (bf16 out)
// ---------------------------------------------------------------------------
__global__ __launch_bounds__(256) void xproj_gemm(
    const float* __restrict__ x, const float* __restrict__ w_ih,
    bf16* __restrict__ xproj)
{
    __shared__ bf16 As[128 * 40];
    __shared__ bf16 Bs[128 * 40];
    const int tid = threadIdx.x;
    const int m0 = blockIdx.x * 128;
    const int n0 = blockIdx.y * 128;
    const int w = tid >> 6, lane = tid & 63;
    const int r = lane & 15, q = lane >> 4;

    f32x4 acc[2][8];
    #pragma unroll
    for (int i = 0; i < 2; i++)
        #pragma unroll
        for (int j = 0; j < 8; j++)
            acc[i][j] = (f32x4){0.f, 0.f, 0.f, 0.f};

    for (int kk = 0; kk < 8; kk++) {
        const int k0 = kk * 32;
        __syncthreads();
        #pragma unroll
        for (int j = 0; j < 4; j++) {
            int u = tid + j * 256;
            int row = u >> 3, c4 = u & 7;
            float4 fa = *(const float4*)&x[(size_t)(m0 + row) * DIN + k0 + c4 * 4];
            bf16x4 va = { (bf16)fa.x, (bf16)fa.y, (bf16)fa.z, (bf16)fa.w };
            *(bf16x4*)&As[row * 40 + c4 * 4] = va;
            float4 fb = *(const float4*)&w_ih[(size_t)(n0 + row) * DIN + k0 + c4 * 4];
            bf16x4 vb = { (bf16)fb.x, (bf16)fb.y, (bf16)fb.z, (bf16)fb.w };
            *(bf16x4*)&Bs[row * 40 + c4 * 4] = vb;
        }
        __syncthreads();
        bf16x8 a0 = *(const bf16x8*)&As[(w * 32 + r) * 40 + q * 8];
        bf16x8 a1 = *(const bf16x8*)&As[(w * 32 + 16 + r) * 40 + q * 8];
        #pragma unroll
        for (int nt = 0; nt < 8; nt++) {
            bf16x8 bb = *(const bf16x8*)&Bs[(nt * 16 + r) * 40 + q * 8];
            acc[0][nt] = __builtin_amdgcn_mfma_f32_16x16x32_bf16(a0, bb, acc[0][nt], 0, 0, 0);
            acc[1][nt] = __builtin_amdgcn_mfma_f32_16x16x32_bf16(a1, bb, acc[1][nt], 0, 0, 0);
        }
    }

    #pragma unroll
    for (int mi = 0; mi < 2; mi++)
        #pragma unroll
        for (int nt = 0; nt < 8; nt++)
            #pragma unroll
            for (int reg = 0; reg < 4; reg++) {
                int gm = m0 + w * 32 + mi * 16 + q * 4 + reg;   // x row = b*T + t
                int n  = n0 + nt * 16 + r;
                int b  = gm >> 10, t = gm & 1023;
                xproj[(((t << 6) + b) << 10) + n] = (bf16)acc[mi][nt][reg];
            }
}

// ---------------------------------------------------------------------------
// Kernel 2: persistent recurrence — 4 streams, WAVE-SPECIALIZED, inv+plain-poll.
//
// Round-8 theory: the ~7,150cy/qstep invariant across r2/r3/r7 is the
// sc0sc1-coherent load path (~6,500cy) and/or store-ack FIFO coupling at
// vmcnt(0). Fixes:
//  * polls = agent-acquire fence (s_waitcnt[free] + buffer_inv sc1) + PLAIN
//    cached global_load_dwordx4 + vmcnt(0). Correct because h stores are
//    sc0sc1 write-through to L3 and the inv kills any stale L1/L2 copy.
//  * 6 waves/block: w0-3 compute (ZERO global VMEM -> their vmcnt(0) waits
//    only on their own poll loads, ~L3 RTT), w4 = store wave (reads packed
//    h from LDS, fires sc0sc1 stores, lazy vmcnt(44) guard only), w5 =
//    xproj wave (compiler loads -> LDS staging, one step ahead).
//
// Ring protocol unchanged: hbuf [slot 8][batch 64][feat 1024] bf16; word =
// SENT or final data. Store wave at qstep u stores h produced at u-1: data
// -> slot (t_prev+1)&7, sentinels -> slot (t_prev+4)&7. Sentinel-before-
// data same-address = 12 qsteps apart + vmcnt(44) (11-qstep drain) guard.
// Re-sentinel is 17 qsteps clear of that slot generation's readers (skew
// <=1 step by the dependency chain). Consumer polls data stored >=3 qsteps
// earlier; retries (rare) just loop fence+reload.
// ---------------------------------------------------------------------------

// plain (cached) loads; inv beforehand guarantees freshness. r0-proven
// single-block shape: issue + vmcnt(0) + outputs final at block exit.
#define POLL8(BUF, srcp)                                               \
  asm volatile(                                                        \
    "global_load_dwordx4 %0, %8, off\n\t"                              \
    "global_load_dwordx4 %1, %8, off offset:64\n\t"                    \
    "global_load_dwordx4 %2, %8, off offset:128\n\t"                   \
    "global_load_dwordx4 %3, %8, off offset:192\n\t"                   \
    "global_load_dwordx4 %4, %8, off offset:256\n\t"                   \
    "global_load_dwordx4 %5, %8, off offset:320\n\t"                   \
    "global_load_dwordx4 %6, %8, off offset:384\n\t"                   \
    "global_load_dwordx4 %7, %8, off offset:448\n\t"                   \
    "s_waitcnt vmcnt(0)"                                               \
    : "=&v"(BUF[0]), "=&v"(BUF[1]), "=&v"(BUF[2]), "=&v"(BUF[3]),      \
      "=&v"(BUF[4]), "=&v"(BUF[5]), "=&v"(BUF[6]), "=&v"(BUF[7])       \
    : "v"(srcp) : "memory")

__device__ __forceinline__ int poll_clean4(const i32x4* b)
{
    int ok = 1;
    #pragma unroll
    for (int j = 0; j < 8; j++)
        #pragma unroll
        for (int k2 = 0; k2 < 4; k2++)
            ok &= (b[j][k2] != (int)SENT);
    return __all(ok);
}

// raw workgroup barrier: orders LDS only, leaves VMEM in flight
__device__ __forceinline__ void lds_barrier()
{
    __builtin_amdgcn_sched_barrier(0);
    asm volatile("s_waitcnt lgkmcnt(0)" ::: "memory");
    __builtin_amdgcn_s_barrier();
    __builtin_amdgcn_sched_barrier(0);
}

__global__ __launch_bounds__(384, 1) void rnn_rec(
    const float* __restrict__ w_hh, const float* __restrict__ b_mod,
    const bf16* __restrict__ xproj, u64* __restrict__ hbuf,
    float* __restrict__ hT)
{
    // LS: 128 KB. During init: W tile (64 x 1024 bf16, unpadded). After the
    // B-fragment hoist it is DEAD and reused as scratch:
    //   [0,      4096)  HV packed u32   [parity2][batch16][featpair32]
    //   [4096,  20480)  Xstage bf16     [stream4][parity2][batch16][feat64]
    __shared__ __align__(16) char LS[131072];
    __shared__ f32x4 Red[2][12][64];      // 24.5 KB  [qstep parity][nt*3+sidx][lane]

    const int tid  = threadIdx.x;
    const int f0   = (int)blockIdx.x * 64;
    const int w    = tid >> 6;            // 0-3 compute (kq=w), 4 store, 5 xproj
    const int kq   = w & 3;
    const int lane = tid & 63;
    const int r = lane & 15, q = lane >> 4;

    // ---- init: stage W rows f0..f0+63 (fp32 -> bf16) into LS, all 6 waves ----
    {
        bf16* Wl = (bf16*)LS;
        for (int u = tid; u < 16384; u += 384) {      // float4 units
            int row = u >> 8, c4 = u & 255;
            float4 f = *(const float4*)&w_hh[(size_t)(f0 + row) * HID + c4 * 4];
            bf16x4 v = { (bf16)f.x, (bf16)f.y, (bf16)f.z, (bf16)f.w };
            *(bf16x4*)&Wl[row * 1024 + c4 * 4] = v;
        }
    }
    const int myF = f0 + kq * 16 + r;
    const float bc = b_mod[myF];
    __syncthreads();

    // compute waves: hoist B fragments (loop-invariant, 128 VGPRs)
    bf16x8 Bf[4][8];
    if (w < 4) {
        const bf16* Wl = (const bf16*)LS;
        #pragma unroll
        for (int nt = 0; nt < 4; nt++)
            #pragma unroll
            for (int ks = 0; ks < 8; ks++)
                Bf[nt][ks] = *(const bf16x8*)&Wl[(nt * 16 + r) * 1024 + kq * 256 + ks * 32 + q * 8];
    }
    __syncthreads();          // Wl dead; LS becomes scratch

    // xproj wave: prologue-stage t=0 for all 4 streams into parity 0
    if (w == 5) {
        #pragma unroll
        for (int s = 0; s < 4; s++) {
            const char* g = (const char*)(xproj
                + (((s * 16 + (lane >> 2)) << 10) + f0 + (lane & 3) * 16));
            i32x4 v0 = *(const i32x4*)g;
            i32x4 v1 = *(const i32x4*)(g + 16);
            char* dst = LS + 4096 + (s * 2 + 0) * 2048 + (lane >> 2) * 128 + (lane & 3) * 32;
            *(i32x4*)dst = v0;
            *(i32x4*)(dst + 16) = v1;
        }
    }
    __syncthreads();

    u32* hbuf32 = (u32*)hbuf;
    const int fragB = r * 2048 + kq * 512 + q * 16;   // per-lane A-frag offset
    const i32x4 sv = { (int)SENT, (int)SENT, (int)SENT, (int)SENT };

    for (int t = 0; t < T_STEPS; t++) {
        #pragma unroll
        for (int s = 0; s < 4; s++) {
            const int par = s & 1;
            lds_barrier();                            // BAR1 of qstep (t,s)

            if (w < 4) {
                // ---- poll: inv + plain loads + vmcnt(0) (queue = polls only) ----
                const char* rsrc = (const char*)hbuf
                    + (size_t)(t & 7) * 131072 + s * 32768 + fragB;
                i32x4 A[8];
                __builtin_amdgcn_fence(__ATOMIC_ACQUIRE, "agent");
                POLL8(A, rsrc);
                int tries = 0;
                while (!poll_clean4(A) && ++tries < (1 << 16)) {
                    __builtin_amdgcn_fence(__ATOMIC_ACQUIRE, "agent");
                    POLL8(A, rsrc);
                }

                // ---- MFMA: z partials, my K-quarter x 4 n-tiles ----
                f32x4 acc[4];
                acc[0] = acc[1] = acc[2] = acc[3] = (f32x4){0.f, 0.f, 0.f, 0.f};
                #pragma unroll
                for (int ks = 0; ks < 8; ks++) {
                    bf16x8 af = __builtin_bit_cast(bf16x8, A[ks]);
                    #pragma unroll
                    for (int nt = 0; nt < 4; nt++)
                        acc[nt] = __builtin_amdgcn_mfma_f32_16x16x32_bf16(
                                      af, Bf[nt][ks], acc[nt], 0, 0, 0);
                }
                // ---- K-partials for other n-tiles -> LDS ----
                #pragma unroll
                for (int nt = 0; nt < 4; nt++) {
                    if (nt == kq) continue;
                    const int sidx = (kq - nt - 1) & 3;
                    Red[par][nt * 3 + sidx][lane] = acc[nt];
                }
                lds_barrier();                        // mid barrier

                // ---- finalize my n-tile ----
                f32x4 z4 = acc[kq];
                #pragma unroll
                for (int si = 0; si < 3; si++)
                    z4 += Red[par][kq * 3 + si][lane];
                const unsigned short* xs = (const unsigned short*)
                    (LS + 4096 + (s * 2 + (t & 1)) * 2048);
                float hv4[4];
                #pragma unroll
                for (int reg = 0; reg < 4; reg++) {
                    u32 xb = xs[(q * 4 + reg) * 64 + kq * 16 + r];
                    float xf = __builtin_bit_cast(float, xb << 16);
                    float z = z4[reg] + xf;
                    hv4[reg] = copysignf(fmaxf(fabsf(z) + bc, 0.0f), z);
                }
                if (t == T_STEPS - 1) {
                    float4 o; o.x = hv4[0]; o.y = hv4[1]; o.z = hv4[2]; o.w = hv4[3];
                    *(float4*)&hT[myF * 64 + s * 16 + q * 4] = o;   // fp32 [H][B]
                } else {
                    // pack bf16 pairs -> HV LDS (store wave picks up next qstep)
                    u32* hv = (u32*)(LS + par * 2048);
                    #pragma unroll
                    for (int reg = 0; reg < 4; reg++) {
                        float other = __shfl_xor(hv4[reg], 1);
                        if ((r & 1) == 0) {
                            u32 lo = (u32)__builtin_bit_cast(unsigned short, (bf16)hv4[reg]);
                            u32 hi = (u32)__builtin_bit_cast(unsigned short, (bf16)other);
                            hv[(q * 4 + reg) * 32 + ((kq * 16 + r) >> 1)] = lo | (hi << 16);
                        }
                    }
                }
            } else if (w == 4) {
                // ---- store wave: flush h produced at qstep u-1 ----
                if (t > 0 || s > 0) {
                    const int t_prev = (s > 0) ? t : t - 1;
                    const int s_prev = (s + 3) & 3;
                    if (t_prev < T_STEPS - 1) {
                        const int pp  = s_prev & 1;
                        const int wp_ = (t_prev + 1) & 7, sp_ = (t_prev + 4) & 7;
                        const u32* hv = (const u32*)(LS + pp * 2048);
                        const int chunk = (lane >> 2) * 32 + (lane & 3) * 8;
                        i32x4 a = *(const i32x4*)&hv[chunk];
                        i32x4 b = *(const i32x4*)&hv[chunk + 4];
                        u32* dp = hbuf32 + (size_t)wp_ * 32768
                                 + (s_prev * 16 + (lane >> 2)) * 512 + (f0 >> 1) + (lane & 3) * 8;
                        u32* sp2 = hbuf32 + (size_t)sp_ * 32768
                                 + (s_prev * 16 + (lane >> 2)) * 512 + (f0 >> 1) + (lane & 3) * 8;
                        asm volatile(
                            "global_store_dwordx4 %3, %0, off sc0 sc1\n\t"
                            "global_store_dwordx4 %3, %1, off offset:16 sc0 sc1\n\t"
                            "global_store_dwordx4 %4, %2, off sc0 sc1\n\t"
                            "global_store_dwordx4 %4, %2, off offset:16 sc0 sc1\n\t"
                            "s_waitcnt vmcnt(44)"
                            :: "v"(a), "v"(b), "v"(sv), "v"(dp), "v"(sp2)
                            : "memory");
                    }
                }
                lds_barrier();                        // mid barrier
            } else {
                // ---- xproj wave: stage (t+1, s) into Xstage[s][(t+1)&1] ----
                if (t + 1 < T_STEPS) {
                    const char* g = (const char*)(xproj
                        + (((size_t)(t + 1) << 16)
                           + ((s * 16 + (lane >> 2)) << 10) + f0 + (lane & 3) * 16));
                    i32x4 v0 = *(const i32x4*)g;
                    i32x4 v1 = *(const i32x4*)(g + 16);
                    char* dst = LS + 4096 + (s * 2 + ((t + 1) & 1)) * 2048
                               + (lane >> 2) * 128 + (lane & 3) * 32;
                    *(i32x4*)dst = v0;
                    *(i32x4*)(dst + 16) = v1;
                }
                lds_barrier();                        // mid barrier
            }
        }
    }
}

// ---------------------------------------------------------------------------
// Kernel 3: out[b][c] = hT[:,b] . w_fc[c,:] + b_fc[c]   (fp32)
// ---------------------------------------------------------------------------
__global__ __launch_bounds__(256) void fc_head(
    const float* __restrict__ hT, const float* __restrict__ w_fc,
    const float* __restrict__ b_fc, float* __restrict__ out)
{
    const int tid = threadIdx.x;
    const int b = tid & 63;
    const int c = blockIdx.x * 4 + (tid >> 6);
    float acc = b_fc[c];
    #pragma unroll 8
    for (int k = 0; k < HID; k++)
        acc = fmaf(hT[k * 64 + b], w_fc[(size_t)c * HID + k], acc);
    out[b * 1000 + c] = acc;
}

// ---------------------------------------------------------------------------
extern "C" void kernel_launch(void* const* d_in, const int* in_sizes, int n_in,
                              void* d_out, int out_size, void* d_ws, size_t ws_size,
                              hipStream_t stream)
{
    const float* x     = (const float*)d_in[0];
    const float* w_ih  = (const float*)d_in[1];
    const float* w_hh  = (const float*)d_in[2];
    const float* b_mod = (const float*)d_in[3];
    const float* w_fc  = (const float*)d_in[4];
    const float* b_fc  = (const float*)d_in[5];
    float* out = (float*)d_out;

    char* ws = (char*)d_ws;
    // ws layout:
    //   [0, 128 MiB)              xproj bf16  [T][B][H]
    //   [+0, +1 MiB)              hbuf bf16   ring[8][B][H]
    //   [+1 MiB, +1.25 MiB)       hT fp32     [H][B]
    bf16*  xproj = (bf16*)ws;
    u64*   hbuf  = (u64*)(ws + 134217728);
    float* hT    = (float*)(ws + 134217728 + 1048576);

    // ring init: slot 0 = h0 = 0 (valid data), slots 1..7 = sentinel bytes
    hipMemsetAsync(hbuf, 0, 131072, stream);
    hipMemsetAsync((char*)hbuf + 131072, 0x7F, 7 * 131072, stream);

    dim3 g1(512, 8);
    xproj_gemm<<<g1, 256, 0, stream>>>(x, w_ih, xproj);
    rnn_rec<<<NFB, 384, 0, stream>>>(w_hh, b_mod, xproj, hbuf, hT);
    fc_head<<<250, 256, 0, stream>>>(hT, w_fc, b_fc, out);
}